// Round 5
// baseline (171.373 us; speedup 1.0000x reference)
//
#include <hip/hip_runtime.h>
#include <math.h>

#define B 4
#define NP 4096
#define DIM 128
#define CCH 64
#define NS 8

// =============== K_main: transpose + BQ + corr + feat + parts + stats ========
// Blocks 0..511 additionally transpose one 32x128 f2 tile, then release-bump
// ctrs[0]. All 1024 blocks: stage As, BQ shared-scan (overlaps transpose),
// spin on ctrs[0]==512 (acquire), gather f2T rows, write feat + parts.
// Last block to finish (ctrs[1]==1023) reduces parts -> Av/Bv (GroupNorm).
struct KMShared {
  union {
    float tile[128][33];                                  // transpose staging
    struct { float As[16 * 132]; float red[4][14]; } c;   // corr staging
  } u;
  int sidx[128];
  int lastflag;
};

__global__ __launch_bounds__(256, 4) void k_main(
    const float* __restrict__ coords, const float* __restrict__ xyz2,
    const float* __restrict__ f1, const float* __restrict__ f2,
    const float* __restrict__ conv_w, const float* __restrict__ conv_b,
    const float* __restrict__ gamma, const float* __restrict__ beta,
    float* __restrict__ f2T, float* __restrict__ feat,
    float* __restrict__ parts, float* __restrict__ AvBv,
    int* __restrict__ ctrs) {
  __shared__ KMShared sm;
  int blk = blockIdx.x;
  int t = threadIdx.x;
  int bq = (blk & 7) >> 1;
  int chunk = ((blk >> 3) << 1) | (blk & 1);
  int m0 = chunk * 16;

  // ---- phase 0: transpose one tile (blocks 0..511) ----
  if (blk < 512) {
    int b = blk >> 7;
    int n0t = (blk & 127) * 32;
    const float* s = f2 + (size_t)b * DIM * NP;
    float* d = f2T + (size_t)b * NP * DIM;
    int dr = t >> 3, ng = t & 7;
#pragma unroll
    for (int k = 0; k < 4; ++k) {
      int dd = dr + 32 * k;
      float4 v = *(const float4*)&s[(size_t)dd * NP + n0t + ng * 4];
      sm.u.tile[dd][ng * 4 + 0] = v.x;
      sm.u.tile[dd][ng * 4 + 1] = v.y;
      sm.u.tile[dd][ng * 4 + 2] = v.z;
      sm.u.tile[dd][ng * 4 + 3] = v.w;
    }
    __syncthreads();
    int n = t >> 3;
#pragma unroll
    for (int k = 0; k < 4; ++k) {
      int d0 = (t & 7) * 4 + 32 * k;
      float4 w;
      w.x = sm.u.tile[d0 + 0][n];
      w.y = sm.u.tile[d0 + 1][n];
      w.z = sm.u.tile[d0 + 2][n];
      w.w = sm.u.tile[d0 + 3][n];
      *(float4*)&d[(size_t)(n0t + n) * DIM + d0] = w;
    }
    __syncthreads();  // drains stores (barrier implies vmcnt(0)); tile reusable
    if (t == 0) {
      __threadfence();  // release: L2 writeback before the count is visible
      __hip_atomic_fetch_add(&ctrs[0], 1, __ATOMIC_RELAXED,
                             __HIP_MEMORY_SCOPE_AGENT);
    }
  }

  // ---- phase 1: stage f1 columns into As (independent of transpose/BQ) ----
#pragma unroll
  for (int pass = 0; pass < 2; ++pass) {
    int d = pass * 64 + (t >> 2);
    int j4 = t & 3;
    float4 v = *(const float4*)&f1[(size_t)(bq * DIM + d) * NP + m0 + j4 * 4];
    sm.u.c.As[(j4 * 4 + 0) * 132 + d] = v.x;
    sm.u.c.As[(j4 * 4 + 1) * 132 + d] = v.y;
    sm.u.c.As[(j4 * 4 + 2) * 132 + d] = v.z;
    sm.u.c.As[(j4 * 4 + 3) * 132 + d] = v.w;
  }

  // ---- phase 2: ball query, shared scan (4 queries/wave, 2-deep prefetch) --
  {
    int wv = t >> 6, lane = t & 63;
    const float* xz = xyz2 + (size_t)bq * NP * 3;
    float cx[4], cy[4], cz[4];
#pragma unroll
    for (int qi = 0; qi < 4; ++qi) {
      const float* cp = coords + ((size_t)bq * NP + m0 + wv * 4 + qi) * 3;
      cx[qi] = cp[0]; cy[qi] = cp[1]; cz[qi] = cp[2];
    }
    int cnt[4] = {0, 0, 0, 0};
    int first[4] = {0, 0, 0, 0};
    int j0 = lane * 3;
    float ax = xz[j0], ay = xz[j0 + 1], az = xz[j0 + 2];
    int j1 = (64 + lane) * 3;
    float bx = xz[j1], by = xz[j1 + 1], bz = xz[j1 + 2];
#pragma unroll 1
    for (int c = 0; c < 64; c += 2) {
      int c2 = (c + 2 < 64) ? c + 2 : 63;
      int c3 = (c + 3 < 64) ? c + 3 : 63;
      int jn2 = (c2 * 64 + lane) * 3, jn3 = (c3 * 64 + lane) * 3;
      float nax = xz[jn2], nay = xz[jn2 + 1], naz = xz[jn2 + 2];
      float nbx = xz[jn3], nby = xz[jn3 + 1], nbz = xz[jn3 + 2];
#pragma unroll
      for (int qi = 0; qi < 4; ++qi) {
        if (cnt[qi] < NS) {
          // no-fma so the d2<1 boundary matches numpy rounding
          float dx = __fsub_rn(cx[qi], ax);
          float dy = __fsub_rn(cy[qi], ay);
          float dz = __fsub_rn(cz[qi], az);
          float d2 = __fadd_rn(__fadd_rn(__fmul_rn(dx, dx), __fmul_rn(dy, dy)),
                               __fmul_rn(dz, dz));
          bool hit = d2 < 1.0f;
          unsigned long long mk = __ballot(hit);
          if (mk) {
            int rank = cnt[qi] + __popcll(mk & ((1ull << lane) - 1ull));
            if (hit && rank < NS)
              sm.sidx[(wv * 4 + qi) * NS + rank] = c * 64 + lane;
            if (cnt[qi] == 0) first[qi] = c * 64 + (__ffsll(mk) - 1);
            cnt[qi] += __popcll(mk);
          }
        }
      }
      if ((cnt[0] >= NS) & (cnt[1] >= NS) & (cnt[2] >= NS) & (cnt[3] >= NS))
        break;
#pragma unroll
      for (int qi = 0; qi < 4; ++qi) {
        if (cnt[qi] < NS) {
          float dx = __fsub_rn(cx[qi], bx);
          float dy = __fsub_rn(cy[qi], by);
          float dz = __fsub_rn(cz[qi], bz);
          float d2 = __fadd_rn(__fadd_rn(__fmul_rn(dx, dx), __fmul_rn(dy, dy)),
                               __fmul_rn(dz, dz));
          bool hit = d2 < 1.0f;
          unsigned long long mk = __ballot(hit);
          if (mk) {
            int rank = cnt[qi] + __popcll(mk & ((1ull << lane) - 1ull));
            if (hit && rank < NS)
              sm.sidx[(wv * 4 + qi) * NS + rank] = (c + 1) * 64 + lane;
            if (cnt[qi] == 0) first[qi] = (c + 1) * 64 + (__ffsll(mk) - 1);
            cnt[qi] += __popcll(mk);
          }
        }
      }
      if ((cnt[0] >= NS) & (cnt[1] >= NS) & (cnt[2] >= NS) & (cnt[3] >= NS))
        break;
      ax = nax; ay = nay; az = naz;
      bx = nbx; by = nby; bz = nbz;
    }
#pragma unroll
    for (int qi = 0; qi < 4; ++qi) {
      if (lane < NS && lane >= cnt[qi])
        sm.sidx[(wv * 4 + qi) * NS + lane] = first[qi];  // 0 when no hit
    }
  }

  // ---- phase 3: wait for transpose completion (fine-grained, no launch) ----
  if (t == 0) {
    while (__hip_atomic_load(&ctrs[0], __ATOMIC_RELAXED,
                             __HIP_MEMORY_SCOPE_AGENT) < 512)
      __builtin_amdgcn_s_sleep(8);
  }
  __syncthreads();
  __threadfence();  // acquire: invalidate stale L1/L2 before reading f2T

  // ---- phase 4: batched gathers + corr + feat + moment partials ----
  int g = t >> 3;
  int l = t & 7;
  float pm[14];
#pragma unroll
  for (int k = 0; k < 14; ++k) pm[k] = 0.f;
  {
    int id0 = sm.sidx[g], id1 = sm.sidx[32 + g];
    int id2 = sm.sidx[64 + g], id3 = sm.sidx[96 + g];
    const float4* br0 = (const float4*)(f2T + ((size_t)bq * NP + id0) * DIM) + l;
    const float4* br1 = (const float4*)(f2T + ((size_t)bq * NP + id1) * DIM) + l;
    const float4* br2 = (const float4*)(f2T + ((size_t)bq * NP + id2) * DIM) + l;
    const float4* br3 = (const float4*)(f2T + ((size_t)bq * NP + id3) * DIM) + l;
    float4 y00 = br0[0], y01 = br0[8], y02 = br0[16], y03 = br0[24];
    float4 y10 = br1[0], y11 = br1[8], y12 = br1[16], y13 = br1[24];
    const float* xq0 = xyz2 + ((size_t)bq * NP + id0) * 3;
    const float* xq1 = xyz2 + ((size_t)bq * NP + id1) * 3;
    float x0x = xq0[0], x0y = xq0[1], x0z = xq0[2];
    float x1x = xq1[0], x1y = xq1[1], x1z = xq1[2];
    float4 y20 = br2[0], y21 = br2[8], y22 = br2[16], y23 = br2[24];
    float4 y30 = br3[0], y31 = br3[8], y32 = br3[16], y33 = br3[24];
    const float* xq2 = xyz2 + ((size_t)bq * NP + id2) * 3;
    const float* xq3 = xyz2 + ((size_t)bq * NP + id3) * 3;
    float x2x = xq2[0], x2y = xq2[1], x2z = xq2[2];
    float x3x = xq3[0], x3y = xq3[1], x3z = xq3[2];
    size_t fbase = ((size_t)bq * NP + m0) * NS;

#define DO_R(r, ya, yb, yc, yd, nxx, nxy, nxz)                                 \
    {                                                                          \
      int pi = (r) * 32 + g;                                                   \
      int m = pi >> 3;                                                         \
      const float4* arow = (const float4*)&sm.u.c.As[m * 132] + l;             \
      float4 a0 = arow[0], a1 = arow[8], a2 = arow[16], a3 = arow[24];         \
      float acc = a0.x * ya.x + a0.y * ya.y + a0.z * ya.z + a0.w * ya.w +      \
                  a1.x * yb.x + a1.y * yb.y + a1.z * yb.z + a1.w * yb.w +      \
                  a2.x * yc.x + a2.y * yc.y + a2.z * yc.z + a2.w * yc.w +      \
                  a3.x * yd.x + a3.y * yd.y + a3.z * yd.z + a3.w * yd.w;       \
      acc += __shfl_xor(acc, 1);                                               \
      acc += __shfl_xor(acc, 2);                                               \
      acc += __shfl_xor(acc, 4);                                               \
      float corr = acc * 0.08838834764831843f;                                 \
      const float* cpq = coords + ((size_t)bq * NP + m0 + m) * 3;              \
      float dx = nxx - cpq[0], dy = nxy - cpq[1], dz = nxz - cpq[2];           \
      if (l == 0) {                                                            \
        float4 fv;                                                             \
        fv.x = corr; fv.y = dx; fv.z = dy; fv.w = dz;                          \
        ((float4*)feat)[fbase + pi] = fv;                                      \
      }                                                                        \
      pm[0] += corr; pm[1] += dx; pm[2] += dy; pm[3] += dz;                    \
      pm[4] += corr * corr; pm[5] += corr * dx; pm[6] += corr * dy;            \
      pm[7] += corr * dz; pm[8] += dx * dx; pm[9] += dx * dy;                  \
      pm[10] += dx * dz; pm[11] += dy * dy; pm[12] += dy * dz;                 \
      pm[13] += dz * dz;                                                       \
    }
    DO_R(0, y00, y01, y02, y03, x0x, x0y, x0z)
    DO_R(1, y10, y11, y12, y13, x1x, x1y, x1z)
    DO_R(2, y20, y21, y22, y23, x2x, x2y, x2z)
    DO_R(3, y30, y31, y32, y33, x3x, x3y, x3z)
#undef DO_R
  }

#pragma unroll
  for (int k = 0; k < 14; ++k) {
    float v = pm[k];
#pragma unroll
    for (int off = 32; off; off >>= 1) v += __shfl_xor(v, off);
    pm[k] = v;
  }
  int lane = t & 63, wvv = t >> 6;
  if (lane == 0) {
#pragma unroll
    for (int k = 0; k < 14; ++k) sm.u.c.red[wvv][k] = pm[k];
  }
  __syncthreads();
  if (t < 14) {
    float ssum =
        (sm.u.c.red[0][t] + sm.u.c.red[1][t] + sm.u.c.red[2][t] + sm.u.c.red[3][t]) *
        0.125f;
    parts[((size_t)bq * 256 + chunk) * 14 + t] = ssum;
  }
  __syncthreads();  // drain parts stores (barrier implies vmcnt(0))

  // ---- phase 5: completion count; last block computes GroupNorm stats ----
  if (t == 0) {
    __threadfence();  // release parts
    int old = __hip_atomic_fetch_add(&ctrs[1], 1, __ATOMIC_RELAXED,
                                     __HIP_MEMORY_SCOPE_AGENT);
    sm.lastflag = (old == 1023) ? 1 : 0;
  }
  __syncthreads();
  if (sm.lastflag) {
    __threadfence();  // acquire all parts
    int w = t >> 6, ln = t & 63;  // wave w handles batch w; lane = channel
    float s[14];
#pragma unroll
    for (int k = 0; k < 14; ++k) s[k] = 0.f;
    const float* pp = parts + (size_t)w * 256 * 14;
#pragma unroll
    for (int j = 0; j < 4; ++j) {
      int base = (ln + 64 * j) * 14;
#pragma unroll
      for (int k = 0; k < 14; ++k) s[k] += pp[base + k];
    }
#pragma unroll
    for (int k = 0; k < 14; ++k) {
#pragma unroll
      for (int off = 32; off; off >>= 1) s[k] += __shfl_xor(s[k], off);
    }
    int o = ln;
    float w0 = conv_w[o * 4 + 0], w1 = conv_w[o * 4 + 1];
    float w2 = conv_w[o * 4 + 2], w3 = conv_w[o * 4 + 3];
    float bo = conv_b[o];
    const float cnt = (float)(NP * NS);
    float wS1 = w0 * s[0] + w1 * s[1] + w2 * s[2] + w3 * s[3];
    float q = w0 * w0 * s[4] + w1 * w1 * s[8] + w2 * w2 * s[11] +
              w3 * w3 * s[13] +
              2.f * (w0 * w1 * s[5] + w0 * w2 * s[6] + w0 * w3 * s[7] +
                     w1 * w2 * s[9] + w1 * w3 * s[10] + w2 * w3 * s[12]);
    float SxA = wS1 + bo * cnt;
    float SxxA = q + 2.f * bo * wS1 + bo * bo * cnt;
    // group-of-8 reduce within the wave (channels o = g*8+k are lanes g*8+k)
    float gs = SxA, g2 = SxxA;
#pragma unroll
    for (int off = 1; off < 8; off <<= 1) {
      gs += __shfl_xor(gs, off);
      g2 += __shfl_xor(g2, off);
    }
    float mean = gs / (cnt * 8.f);
    float e2 = g2 / (cnt * 8.f);
    float var = e2 - mean * mean;
    float inv = rsqrtf(var + 1e-5f);
    float A = gamma[o] * inv;
    AvBv[w * 64 + o] = A;
    AvBv[256 + w * 64 + o] = beta[o] - mean * A;
  }
}

// =============== K_out (lean): conv+GN-affine+PReLU+max + out GEMM ==========
__global__ __launch_bounds__(256) void kB_out_lean(
    const float* __restrict__ feat, const float* __restrict__ AvBv,
    const float* __restrict__ conv_w, const float* __restrict__ conv_b,
    const float* __restrict__ prelu, const float* __restrict__ out_w,
    const float* __restrict__ out_b, float* __restrict__ out) {
  int b = blockIdx.x >> 8;
  int n0 = (blockIdx.x & 255) * 16;
  __shared__ float4 fs4[16 * 8];
  __shared__ float4 vs4[16 * 16];
  __shared__ float4 ow4[64 * 16];
  __shared__ float cw[256], cb_[64], Av[64], Bv[64], ob_[64];
  int t = threadIdx.x;
  if (t < 128) fs4[t] = ((const float4*)(feat + ((size_t)b * NP + n0) * 32))[t];
  {
    const float4* src = (const float4*)out_w;
#pragma unroll
    for (int k = 0; k < 4; ++k) {
      int i4 = t + k * 256;
      int oo = i4 >> 4, gg = i4 & 15;
      ow4[oo * 16 + (gg ^ ((oo >> 2) & 7))] = src[i4];
    }
  }
  cw[t] = conv_w[t];
  if (t < 64) {
    cb_[t] = conv_b[t];
    ob_[t] = out_b[t];
    Av[t] = AvBv[b * 64 + t];
    Bv[t] = AvBv[256 + b * 64 + t];
  }
  float alpha = prelu[0];
  __syncthreads();
  {
    int o = t & 63;
    int pw = t >> 6;
    float w0 = cw[o * 4 + 0], w1 = cw[o * 4 + 1];
    float w2 = cw[o * 4 + 2], w3 = cw[o * 4 + 3];
    float A = Av[o], Bc = Bv[o], bb = cb_[o];
    float* vsf = (float*)vs4;
#pragma unroll
    for (int i = 0; i < 4; ++i) {
      int p = pw * 4 + i;
      float mx = -INFINITY;
#pragma unroll
      for (int s = 0; s < NS; ++s) {
        float4 f = fs4[p * 8 + s];
        float x = fmaf(w0, f.x, fmaf(w1, f.y, fmaf(w2, f.z, fmaf(w3, f.w, bb))));
        float y = fmaf(A, x, Bc);
        y = (y >= 0.f) ? y : alpha * y;
        mx = fmaxf(mx, y);
      }
      vsf[(p * 16 + ((o >> 2) ^ ((p >> 2) & 7))) * 4 + (o & 3)] = mx;
    }
  }
  __syncthreads();
  {
    int ti = t >> 3;
    int tj = t & 7;
    float acc[2][2];
#pragma unroll
    for (int oi = 0; oi < 2; ++oi)
#pragma unroll
      for (int pj = 0; pj < 2; ++pj) acc[oi][pj] = 0.f;
#pragma unroll
    for (int g = 0; g < 16; ++g) {
      float4 vv[2], ww[2];
#pragma unroll
      for (int pj = 0; pj < 2; ++pj) {
        int p = tj * 2 + pj;
        vv[pj] = vs4[p * 16 + (g ^ ((p >> 2) & 7))];
      }
#pragma unroll
      for (int oi = 0; oi < 2; ++oi) {
        int oo = ti * 2 + oi;
        ww[oi] = ow4[oo * 16 + (g ^ ((oo >> 2) & 7))];
      }
#pragma unroll
      for (int oi = 0; oi < 2; ++oi)
#pragma unroll
        for (int pj = 0; pj < 2; ++pj) {
          acc[oi][pj] = fmaf(ww[oi].x, vv[pj].x, acc[oi][pj]);
          acc[oi][pj] = fmaf(ww[oi].y, vv[pj].y, acc[oi][pj]);
          acc[oi][pj] = fmaf(ww[oi].z, vv[pj].z, acc[oi][pj]);
          acc[oi][pj] = fmaf(ww[oi].w, vv[pj].w, acc[oi][pj]);
        }
    }
#pragma unroll
    for (int oi = 0; oi < 2; ++oi) {
      int oo = ti * 2 + oi;
      float bb = ob_[oo];
      float2 r;
      r.x = acc[oi][0] + bb;
      r.y = acc[oi][1] + bb;
      *(float2*)&out[((size_t)b * CCH + oo) * NP + n0 + tj * 2] = r;
    }
  }
}

// =============== fallback path (tiny workspace): R3 kernels =================
__global__ __launch_bounds__(256) void k_bqcorr_fb(
    const float* __restrict__ coords, const float* __restrict__ xyz2,
    const float* __restrict__ f1, const float* __restrict__ f2,
    float* __restrict__ feat, float* __restrict__ parts) {
  int blk = blockIdx.x;
  int t = threadIdx.x;
  int bq = (blk & 7) >> 1;
  int chunk = ((blk >> 3) << 1) | (blk & 1);
  int m0 = chunk * 16;
  __shared__ int sidx[128];
  __shared__ float red[4][14];
  {
    int wv = t >> 6, lane = t & 63;
    const float* xz = xyz2 + (size_t)bq * NP * 3;
    float cx[4], cy[4], cz[4];
#pragma unroll
    for (int qi = 0; qi < 4; ++qi) {
      const float* cp = coords + ((size_t)bq * NP + m0 + wv * 4 + qi) * 3;
      cx[qi] = cp[0]; cy[qi] = cp[1]; cz[qi] = cp[2];
    }
    int cnt[4] = {0, 0, 0, 0};
    int first[4] = {0, 0, 0, 0};
#pragma unroll 1
    for (int c = 0; c < 64; ++c) {
      int j = (c * 64 + lane) * 3;
      float px = xz[j], py = xz[j + 1], pz = xz[j + 2];
#pragma unroll
      for (int qi = 0; qi < 4; ++qi) {
        if (cnt[qi] < NS) {
          float dx = __fsub_rn(cx[qi], px);
          float dy = __fsub_rn(cy[qi], py);
          float dz = __fsub_rn(cz[qi], pz);
          float d2 = __fadd_rn(__fadd_rn(__fmul_rn(dx, dx), __fmul_rn(dy, dy)),
                               __fmul_rn(dz, dz));
          bool hit = d2 < 1.0f;
          unsigned long long mk = __ballot(hit);
          if (mk) {
            int rank = cnt[qi] + __popcll(mk & ((1ull << lane) - 1ull));
            if (hit && rank < NS) sidx[(wv * 4 + qi) * NS + rank] = c * 64 + lane;
            if (cnt[qi] == 0) first[qi] = c * 64 + (__ffsll(mk) - 1);
            cnt[qi] += __popcll(mk);
          }
        }
      }
      if ((cnt[0] >= NS) & (cnt[1] >= NS) & (cnt[2] >= NS) & (cnt[3] >= NS))
        break;
    }
#pragma unroll
    for (int qi = 0; qi < 4; ++qi) {
      if (lane < NS && lane >= cnt[qi])
        sidx[(wv * 4 + qi) * NS + lane] = first[qi];
    }
  }
  __syncthreads();
  int g = t >> 3;
  int l = t & 7;
  float pm[14];
#pragma unroll
  for (int k = 0; k < 14; ++k) pm[k] = 0.f;
#pragma unroll
  for (int r = 0; r < 4; ++r) {
    int pi = r * 32 + g;
    int m = pi >> 3, s = pi & 7;
    int id = sidx[r * 32 + g];
    float acc = 0.f;
#pragma unroll
    for (int k = 0; k < 4; ++k) {
#pragma unroll
      for (int c = 0; c < 4; ++c) {
        int d = (l + 8 * k) * 4 + c;
        acc += f1[(size_t)(bq * DIM + d) * NP + m0 + m] *
               f2[(size_t)(bq * DIM + d) * NP + id];
      }
    }
    acc += __shfl_xor(acc, 1);
    acc += __shfl_xor(acc, 2);
    acc += __shfl_xor(acc, 4);
    float corr = acc * 0.08838834764831843f;
    const float* cpq = coords + ((size_t)bq * NP + m0 + m) * 3;
    const float* xp = xyz2 + ((size_t)bq * NP + id) * 3;
    float dx = xp[0] - cpq[0], dy = xp[1] - cpq[1], dz = xp[2] - cpq[2];
    if (l == 0) {
      float4 fv;
      fv.x = corr; fv.y = dx; fv.z = dy; fv.w = dz;
      ((float4*)feat)[((size_t)bq * NP + m0 + m) * NS + s] = fv;
    }
    pm[0] += corr; pm[1] += dx; pm[2] += dy; pm[3] += dz;
    pm[4] += corr * corr; pm[5] += corr * dx; pm[6] += corr * dy;
    pm[7] += corr * dz; pm[8] += dx * dx; pm[9] += dx * dy;
    pm[10] += dx * dz; pm[11] += dy * dy; pm[12] += dy * dz; pm[13] += dz * dz;
  }
#pragma unroll
  for (int k = 0; k < 14; ++k) {
    float v = pm[k];
#pragma unroll
    for (int off = 32; off; off >>= 1) v += __shfl_xor(v, off);
    pm[k] = v;
  }
  int lane = t & 63, wvv = t >> 6;
  if (lane == 0) {
#pragma unroll
    for (int k = 0; k < 14; ++k) red[wvv][k] = pm[k];
  }
  __syncthreads();
  if (t < 14) {
    float ssum = (red[0][t] + red[1][t] + red[2][t] + red[3][t]) * 0.125f;
    parts[((size_t)bq * 256 + chunk) * 14 + t] = ssum;
  }
}

__global__ __launch_bounds__(256) void kB_out_full(
    const float* __restrict__ feat, const float* __restrict__ parts,
    const float* __restrict__ conv_w, const float* __restrict__ conv_b,
    const float* __restrict__ gamma, const float* __restrict__ beta,
    const float* __restrict__ prelu, const float* __restrict__ out_w,
    const float* __restrict__ out_b, float* __restrict__ out) {
  int b = blockIdx.x >> 8;
  int n0 = (blockIdx.x & 255) * 16;
  __shared__ float4 fs4[16 * 8];
  __shared__ float4 vs4[16 * 16];
  __shared__ float4 ow4[64 * 16];
  __shared__ float cw[256], cb_[64], Av[64], Bv[64], ob_[64];
  __shared__ float red2[8][14];
  __shared__ float Sm[14];
  __shared__ float SxA[64], SxxA[64];
  int t = threadIdx.x;
  if (t < 128) fs4[t] = ((const float4*)(feat + ((size_t)b * NP + n0) * 32))[t];
  {
    const float4* src = (const float4*)out_w;
#pragma unroll
    for (int k = 0; k < 4; ++k) {
      int i4 = t + k * 256;
      int oo = i4 >> 4, gg = i4 & 15;
      ow4[oo * 16 + (gg ^ ((oo >> 2) & 7))] = src[i4];
    }
  }
  cw[t] = conv_w[t];
  if (t < 64) {
    cb_[t] = conv_b[t];
    ob_[t] = out_b[t];
  }
  if (t < 112) {
    int k = t % 14, jg = t / 14;
    float s = 0.f;
    const float* pp = parts + ((size_t)b * 256 + jg * 32) * 14 + k;
#pragma unroll 8
    for (int j = 0; j < 32; ++j) s += pp[j * 14];
    red2[jg][k] = s;
  }
  float alpha = prelu[0];
  __syncthreads();
  if (t < 14) {
    float s = 0.f;
#pragma unroll
    for (int jg = 0; jg < 8; ++jg) s += red2[jg][t];
    Sm[t] = s;
  }
  __syncthreads();
  if (t < 64) {
    int o = t;
    float w0 = cw[o * 4 + 0], w1 = cw[o * 4 + 1];
    float w2 = cw[o * 4 + 2], w3 = cw[o * 4 + 3];
    float bo = cb_[o];
    const float cnt = (float)(NP * NS);
    float wS1 = w0 * Sm[0] + w1 * Sm[1] + w2 * Sm[2] + w3 * Sm[3];
    float q = w0 * w0 * Sm[4] + w1 * w1 * Sm[8] + w2 * w2 * Sm[11] +
              w3 * w3 * Sm[13] +
              2.f * (w0 * w1 * Sm[5] + w0 * w2 * Sm[6] + w0 * w3 * Sm[7] +
                     w1 * w2 * Sm[9] + w1 * w3 * Sm[10] + w2 * w3 * Sm[12]);
    SxA[o] = wS1 + bo * cnt;
    SxxA[o] = q + 2.f * bo * wS1 + bo * bo * cnt;
  }
  __syncthreads();
  if (t < 64) {
    int o = t, g = o >> 3;
    const float cnt = (float)(NP * NS);
    float sm = 0.f, s2 = 0.f;
#pragma unroll
    for (int k = 0; k < 8; ++k) {
      sm += SxA[g * 8 + k];
      s2 += SxxA[g * 8 + k];
    }
    float mean = sm / (cnt * 8.f);
    float e2 = s2 / (cnt * 8.f);
    float var = e2 - mean * mean;
    float inv = rsqrtf(var + 1e-5f);
    float A = gamma[o] * inv;
    Av[o] = A;
    Bv[o] = beta[o] - mean * A;
  }
  __syncthreads();
  {
    int o = t & 63;
    int pw = t >> 6;
    float w0 = cw[o * 4 + 0], w1 = cw[o * 4 + 1];
    float w2 = cw[o * 4 + 2], w3 = cw[o * 4 + 3];
    float A = Av[o], Bc = Bv[o], bb = cb_[o];
    float* vsf = (float*)vs4;
#pragma unroll
    for (int i = 0; i < 4; ++i) {
      int p = pw * 4 + i;
      float mx = -INFINITY;
#pragma unroll
      for (int s = 0; s < NS; ++s) {
        float4 f = fs4[p * 8 + s];
        float x = fmaf(w0, f.x, fmaf(w1, f.y, fmaf(w2, f.z, fmaf(w3, f.w, bb))));
        float y = fmaf(A, x, Bc);
        y = (y >= 0.f) ? y : alpha * y;
        mx = fmaxf(mx, y);
      }
      vsf[(p * 16 + ((o >> 2) ^ ((p >> 2) & 7))) * 4 + (o & 3)] = mx;
    }
  }
  __syncthreads();
  {
    int ti = t >> 3;
    int tj = t & 7;
    float acc[2][2];
#pragma unroll
    for (int oi = 0; oi < 2; ++oi)
#pragma unroll
      for (int pj = 0; pj < 2; ++pj) acc[oi][pj] = 0.f;
#pragma unroll
    for (int g = 0; g < 16; ++g) {
      float4 vv[2], ww[2];
#pragma unroll
      for (int pj = 0; pj < 2; ++pj) {
        int p = tj * 2 + pj;
        vv[pj] = vs4[p * 16 + (g ^ ((p >> 2) & 7))];
      }
#pragma unroll
      for (int oi = 0; oi < 2; ++oi) {
        int oo = ti * 2 + oi;
        ww[oi] = ow4[oo * 16 + (g ^ ((oo >> 2) & 7))];
      }
#pragma unroll
      for (int oi = 0; oi < 2; ++oi)
#pragma unroll
        for (int pj = 0; pj < 2; ++pj) {
          acc[oi][pj] = fmaf(ww[oi].x, vv[pj].x, acc[oi][pj]);
          acc[oi][pj] = fmaf(ww[oi].y, vv[pj].y, acc[oi][pj]);
          acc[oi][pj] = fmaf(ww[oi].z, vv[pj].z, acc[oi][pj]);
          acc[oi][pj] = fmaf(ww[oi].w, vv[pj].w, acc[oi][pj]);
        }
    }
#pragma unroll
    for (int oi = 0; oi < 2; ++oi) {
      int oo = ti * 2 + oi;
      float bb = ob_[oo];
      float2 r;
      r.x = acc[oi][0] + bb;
      r.y = acc[oi][1] + bb;
      *(float2*)&out[((size_t)b * CCH + oo) * NP + n0 + tj * 2] = r;
    }
  }
}

extern "C" void kernel_launch(void* const* d_in, const int* in_sizes, int n_in,
                              void* d_out, int out_size, void* d_ws, size_t ws_size,
                              hipStream_t stream) {
  const float* coords = (const float*)d_in[0];
  const float* xyz2 = (const float*)d_in[1];
  const float* fmap1 = (const float*)d_in[2];
  const float* fmap2 = (const float*)d_in[3];
  const float* conv_w = (const float*)d_in[4];
  const float* conv_b = (const float*)d_in[5];
  const float* gamma = (const float*)d_in[6];
  const float* beta = (const float*)d_in[7];
  const float* prelu = (const float*)d_in[8];
  const float* out_w = (const float*)d_in[9];
  const float* out_b = (const float*)d_in[10];
  float* out = (float*)d_out;
  float* ws = (float*)d_ws;

  const size_t BND = (size_t)B * NP * DIM;     // f2T
  const size_t FEAT = (size_t)B * NP * NS * 4; // feat
  const size_t PARTS = (size_t)B * 256 * 14;   // moment partials
  size_t needT = (BND + FEAT + PARTS + 512 + 64) * sizeof(float);
  int useT = (ws_size >= needT) ? 1 : 0;

  float* f2T = ws;
  float* featp = useT ? (f2T + BND) : ws;
  float* parts = featp + FEAT;
  float* AvBv = parts + PARTS;
  int* ctrs = (int*)(AvBv + 512);

  if (useT) {
    hipMemsetAsync(ctrs, 0, 16, stream);
    k_main<<<dim3(1024), dim3(256), 0, stream>>>(
        coords, xyz2, fmap1, fmap2, conv_w, conv_b, gamma, beta, f2T, featp,
        parts, AvBv, ctrs);
    kB_out_lean<<<dim3(B * (NP / 16)), dim3(256), 0, stream>>>(
        featp, AvBv, conv_w, conv_b, prelu, out_w, out_b, out);
  } else {
    k_bqcorr_fb<<<dim3(1024), dim3(256), 0, stream>>>(coords, xyz2, fmap1,
                                                      fmap2, featp, parts);
    kB_out_full<<<dim3(B * (NP / 16)), dim3(256), 0, stream>>>(
        featp, parts, conv_w, conv_b, gamma, beta, prelu, out_w, out_b, out);
  }
}

// Round 6
// 41.212 us; speedup vs baseline: 4.1584x; 4.1584x over previous
//
#include <hip/hip_runtime.h>
#include <math.h>

#define B 4
#define NP 4096
#define DIM 128
#define CCH 64
#define NS 8

// ==================== K1: f2 transpose (512 blocks x 256) ====================
// [b][d][n] -> f2T [b][n][d], 32-n x 128-d tiles. Proven code.
__global__ __launch_bounds__(256) void k_transpose(
    const float* __restrict__ f2, float* __restrict__ o2) {
  int tb = blockIdx.x;
  int t = threadIdx.x;
  __shared__ float tile[128][33];
  int b = tb >> 7;
  int n0 = (tb & 127) * 32;
  const float* s = f2 + (size_t)b * DIM * NP;
  float* d = o2 + (size_t)b * NP * DIM;
  int dr = t >> 3;
  int ng = t & 7;
#pragma unroll
  for (int k = 0; k < 4; ++k) {
    int dd = dr + 32 * k;
    float4 v = *(const float4*)&s[(size_t)dd * NP + n0 + ng * 4];
    tile[dd][ng * 4 + 0] = v.x;
    tile[dd][ng * 4 + 1] = v.y;
    tile[dd][ng * 4 + 2] = v.z;
    tile[dd][ng * 4 + 3] = v.w;
  }
  __syncthreads();
  int n = t >> 3;
#pragma unroll
  for (int k = 0; k < 4; ++k) {
    int d0 = (t & 7) * 4 + 32 * k;
    float4 w;
    w.x = tile[d0 + 0][n];
    w.y = tile[d0 + 1][n];
    w.z = tile[d0 + 2][n];
    w.w = tile[d0 + 3][n];
    *(float4*)&d[(size_t)(n0 + n) * DIM + d0] = w;
  }
}

// ============ K2: ball query + corr + feat + moment partials (1024 x 256) ====
// BQ shared-scan (4 queries/wave simultaneously, 2-deep prefetch) -> sidx in
// LDS only (no global idx round trip). Then batched f2T gathers.
__global__ __launch_bounds__(256) void k_bqcorr(
    const float* __restrict__ coords, const float* __restrict__ xyz2,
    const float* __restrict__ f1, const float* __restrict__ f2,
    const float* __restrict__ f2T, float* __restrict__ feat,
    float* __restrict__ parts, int trans) {
  int blk = blockIdx.x;
  int t = threadIdx.x;
  int bq = (blk & 7) >> 1;
  int chunk = ((blk >> 3) << 1) | (blk & 1);
  int m0 = chunk * 16;
  __shared__ float As[16 * 132];
  __shared__ int sidx[128];
  __shared__ float red[4][14];

  // ---- stage f1 columns m0..m0+15 into As (independent of BQ) ----
  if (trans) {
#pragma unroll
    for (int pass = 0; pass < 2; ++pass) {
      int d = pass * 64 + (t >> 2);
      int j4 = t & 3;
      float4 v = *(const float4*)&f1[(size_t)(bq * DIM + d) * NP + m0 + j4 * 4];
      As[(j4 * 4 + 0) * 132 + d] = v.x;
      As[(j4 * 4 + 1) * 132 + d] = v.y;
      As[(j4 * 4 + 2) * 132 + d] = v.z;
      As[(j4 * 4 + 3) * 132 + d] = v.w;
    }
  }

  // ---- ball query: shared scan, 4 queries/wave at once ----
  {
    int wv = t >> 6, lane = t & 63;
    const float* xz = xyz2 + (size_t)bq * NP * 3;
    float cx[4], cy[4], cz[4];
#pragma unroll
    for (int qi = 0; qi < 4; ++qi) {
      const float* cp = coords + ((size_t)bq * NP + m0 + wv * 4 + qi) * 3;
      cx[qi] = cp[0]; cy[qi] = cp[1]; cz[qi] = cp[2];
    }
    int cnt[4] = {0, 0, 0, 0};
    int first[4] = {0, 0, 0, 0};
    int j0 = lane * 3;
    float ax = xz[j0], ay = xz[j0 + 1], az = xz[j0 + 2];
    int j1 = (64 + lane) * 3;
    float bx = xz[j1], by = xz[j1 + 1], bz = xz[j1 + 2];
#pragma unroll 1
    for (int c = 0; c < 64; c += 2) {
      int c2 = (c + 2 < 64) ? c + 2 : 63;
      int c3 = (c + 3 < 64) ? c + 3 : 63;
      int jn2 = (c2 * 64 + lane) * 3, jn3 = (c3 * 64 + lane) * 3;
      float nax = xz[jn2], nay = xz[jn2 + 1], naz = xz[jn2 + 2];
      float nbx = xz[jn3], nby = xz[jn3 + 1], nbz = xz[jn3 + 2];
#pragma unroll
      for (int qi = 0; qi < 4; ++qi) {
        if (cnt[qi] < NS) {
          // no-fma so the d2<1 boundary matches numpy rounding
          float dx = __fsub_rn(cx[qi], ax);
          float dy = __fsub_rn(cy[qi], ay);
          float dz = __fsub_rn(cz[qi], az);
          float d2 = __fadd_rn(__fadd_rn(__fmul_rn(dx, dx), __fmul_rn(dy, dy)),
                               __fmul_rn(dz, dz));
          bool hit = d2 < 1.0f;
          unsigned long long mk = __ballot(hit);
          if (mk) {
            int rank = cnt[qi] + __popcll(mk & ((1ull << lane) - 1ull));
            if (hit && rank < NS)
              sidx[(wv * 4 + qi) * NS + rank] = c * 64 + lane;
            if (cnt[qi] == 0) first[qi] = c * 64 + (__ffsll(mk) - 1);
            cnt[qi] += __popcll(mk);
          }
        }
      }
      if ((cnt[0] >= NS) & (cnt[1] >= NS) & (cnt[2] >= NS) & (cnt[3] >= NS))
        break;
#pragma unroll
      for (int qi = 0; qi < 4; ++qi) {
        if (cnt[qi] < NS) {
          float dx = __fsub_rn(cx[qi], bx);
          float dy = __fsub_rn(cy[qi], by);
          float dz = __fsub_rn(cz[qi], bz);
          float d2 = __fadd_rn(__fadd_rn(__fmul_rn(dx, dx), __fmul_rn(dy, dy)),
                               __fmul_rn(dz, dz));
          bool hit = d2 < 1.0f;
          unsigned long long mk = __ballot(hit);
          if (mk) {
            int rank = cnt[qi] + __popcll(mk & ((1ull << lane) - 1ull));
            if (hit && rank < NS)
              sidx[(wv * 4 + qi) * NS + rank] = (c + 1) * 64 + lane;
            if (cnt[qi] == 0) first[qi] = (c + 1) * 64 + (__ffsll(mk) - 1);
            cnt[qi] += __popcll(mk);
          }
        }
      }
      if ((cnt[0] >= NS) & (cnt[1] >= NS) & (cnt[2] >= NS) & (cnt[3] >= NS))
        break;
      ax = nax; ay = nay; az = naz;
      bx = nbx; by = nby; bz = nbz;
    }
#pragma unroll
    for (int qi = 0; qi < 4; ++qi) {
      if (lane < NS && lane >= cnt[qi])
        sidx[(wv * 4 + qi) * NS + lane] = first[qi];  // 0 when no hit
    }
  }
  __syncthreads();

  // ---- gathers + corr + feat + moment partials ----
  int g = t >> 3;
  int l = t & 7;
  float pm[14];
#pragma unroll
  for (int k = 0; k < 14; ++k) pm[k] = 0.f;

  if (trans) {
    int id0 = sidx[g], id1 = sidx[32 + g];
    int id2 = sidx[64 + g], id3 = sidx[96 + g];
    const float4* br0 = (const float4*)(f2T + ((size_t)bq * NP + id0) * DIM) + l;
    const float4* br1 = (const float4*)(f2T + ((size_t)bq * NP + id1) * DIM) + l;
    const float4* br2 = (const float4*)(f2T + ((size_t)bq * NP + id2) * DIM) + l;
    const float4* br3 = (const float4*)(f2T + ((size_t)bq * NP + id3) * DIM) + l;
    float4 y00 = br0[0], y01 = br0[8], y02 = br0[16], y03 = br0[24];
    float4 y10 = br1[0], y11 = br1[8], y12 = br1[16], y13 = br1[24];
    const float* xq0 = xyz2 + ((size_t)bq * NP + id0) * 3;
    const float* xq1 = xyz2 + ((size_t)bq * NP + id1) * 3;
    float x0x = xq0[0], x0y = xq0[1], x0z = xq0[2];
    float x1x = xq1[0], x1y = xq1[1], x1z = xq1[2];
    float4 y20 = br2[0], y21 = br2[8], y22 = br2[16], y23 = br2[24];
    float4 y30 = br3[0], y31 = br3[8], y32 = br3[16], y33 = br3[24];
    const float* xq2 = xyz2 + ((size_t)bq * NP + id2) * 3;
    const float* xq3 = xyz2 + ((size_t)bq * NP + id3) * 3;
    float x2x = xq2[0], x2y = xq2[1], x2z = xq2[2];
    float x3x = xq3[0], x3y = xq3[1], x3z = xq3[2];
    size_t fbase = ((size_t)bq * NP + m0) * NS;

#define DO_R(r, ya, yb, yc, yd, nxx, nxy, nxz)                                 \
    {                                                                          \
      int pi = (r) * 32 + g;                                                   \
      int m = pi >> 3;                                                         \
      const float4* arow = (const float4*)&As[m * 132] + l;                    \
      float4 a0 = arow[0], a1 = arow[8], a2 = arow[16], a3 = arow[24];         \
      float acc = a0.x * ya.x + a0.y * ya.y + a0.z * ya.z + a0.w * ya.w +      \
                  a1.x * yb.x + a1.y * yb.y + a1.z * yb.z + a1.w * yb.w +      \
                  a2.x * yc.x + a2.y * yc.y + a2.z * yc.z + a2.w * yc.w +      \
                  a3.x * yd.x + a3.y * yd.y + a3.z * yd.z + a3.w * yd.w;       \
      acc += __shfl_xor(acc, 1);                                               \
      acc += __shfl_xor(acc, 2);                                               \
      acc += __shfl_xor(acc, 4);                                               \
      float corr = acc * 0.08838834764831843f;                                 \
      const float* cpq = coords + ((size_t)bq * NP + m0 + m) * 3;              \
      float dx = nxx - cpq[0], dy = nxy - cpq[1], dz = nxz - cpq[2];           \
      if (l == 0) {                                                            \
        float4 fv;                                                             \
        fv.x = corr; fv.y = dx; fv.z = dy; fv.w = dz;                          \
        ((float4*)feat)[fbase + pi] = fv;                                      \
      }                                                                        \
      pm[0] += corr; pm[1] += dx; pm[2] += dy; pm[3] += dz;                    \
      pm[4] += corr * corr; pm[5] += corr * dx; pm[6] += corr * dy;            \
      pm[7] += corr * dz; pm[8] += dx * dx; pm[9] += dx * dy;                  \
      pm[10] += dx * dz; pm[11] += dy * dy; pm[12] += dy * dz;                 \
      pm[13] += dz * dz;                                                       \
    }
    DO_R(0, y00, y01, y02, y03, x0x, x0y, x0z)
    DO_R(1, y10, y11, y12, y13, x1x, x1y, x1z)
    DO_R(2, y20, y21, y22, y23, x2x, x2y, x2z)
    DO_R(3, y30, y31, y32, y33, x3x, x3y, x3z)
#undef DO_R
  } else {
    int idv[4];
#pragma unroll
    for (int r = 0; r < 4; ++r) idv[r] = sidx[r * 32 + g];
#pragma unroll
    for (int r = 0; r < 4; ++r) {
      int pi = r * 32 + g;
      int m = pi >> 3, s = pi & 7;
      int id = idv[r];
      float acc = 0.f;
#pragma unroll
      for (int k = 0; k < 4; ++k) {
#pragma unroll
        for (int c = 0; c < 4; ++c) {
          int d = (l + 8 * k) * 4 + c;
          acc += f1[(size_t)(bq * DIM + d) * NP + m0 + m] *
                 f2[(size_t)(bq * DIM + d) * NP + id];
        }
      }
      acc += __shfl_xor(acc, 1);
      acc += __shfl_xor(acc, 2);
      acc += __shfl_xor(acc, 4);
      float corr = acc * 0.08838834764831843f;
      const float* cpq = coords + ((size_t)bq * NP + m0 + m) * 3;
      const float* xp = xyz2 + ((size_t)bq * NP + id) * 3;
      float dx = xp[0] - cpq[0], dy = xp[1] - cpq[1], dz = xp[2] - cpq[2];
      if (l == 0) {
        float4 fv;
        fv.x = corr; fv.y = dx; fv.z = dy; fv.w = dz;
        ((float4*)feat)[((size_t)bq * NP + m0 + m) * NS + s] = fv;
      }
      pm[0] += corr; pm[1] += dx; pm[2] += dy; pm[3] += dz;
      pm[4] += corr * corr; pm[5] += corr * dx; pm[6] += corr * dy;
      pm[7] += corr * dz; pm[8] += dx * dx; pm[9] += dx * dy;
      pm[10] += dx * dz; pm[11] += dy * dy; pm[12] += dy * dz;
      pm[13] += dz * dz;
    }
  }

#pragma unroll
  for (int k = 0; k < 14; ++k) {
    float v = pm[k];
#pragma unroll
    for (int off = 32; off; off >>= 1) v += __shfl_xor(v, off);
    pm[k] = v;
  }
  int lane = t & 63, wvv = t >> 6;
  if (lane == 0) {
#pragma unroll
    for (int k = 0; k < 14; ++k) red[wvv][k] = pm[k];
  }
  __syncthreads();
  if (t < 14) {
    float ssum = (red[0][t] + red[1][t] + red[2][t] + red[3][t]) * 0.125f;
    parts[((size_t)bq * 256 + chunk) * 14 + t] = ssum;
  }
}

// ======== K3: stats + conv+GN+PReLU+max + out GEMM (1024 x 256, proven) =====
__global__ __launch_bounds__(256) void kB_out(
    const float* __restrict__ feat, const float* __restrict__ parts,
    const float* __restrict__ conv_w, const float* __restrict__ conv_b,
    const float* __restrict__ gamma, const float* __restrict__ beta,
    const float* __restrict__ prelu, const float* __restrict__ out_w,
    const float* __restrict__ out_b, float* __restrict__ out) {
  int b = blockIdx.x >> 8;
  int n0 = (blockIdx.x & 255) * 16;
  __shared__ float4 fs4[16 * 8];
  __shared__ float4 vs4[16 * 16];
  __shared__ float4 ow4[64 * 16];
  __shared__ float cw[256], cb_[64], Av[64], Bv[64], ob_[64];
  __shared__ float red2[8][14];
  __shared__ float Sm[14];
  __shared__ float SxA[64], SxxA[64];
  int t = threadIdx.x;
  if (t < 128) fs4[t] = ((const float4*)(feat + ((size_t)b * NP + n0) * 32))[t];
  {
    const float4* src = (const float4*)out_w;
#pragma unroll
    for (int k = 0; k < 4; ++k) {
      int i4 = t + k * 256;
      int oo = i4 >> 4, gg = i4 & 15;
      ow4[oo * 16 + (gg ^ ((oo >> 2) & 7))] = src[i4];
    }
  }
  cw[t] = conv_w[t];
  if (t < 64) {
    cb_[t] = conv_b[t];
    ob_[t] = out_b[t];
  }
  if (t < 112) {
    int k = t % 14, jg = t / 14;
    float s = 0.f;
    const float* pp = parts + ((size_t)b * 256 + jg * 32) * 14 + k;
#pragma unroll 8
    for (int j = 0; j < 32; ++j) s += pp[j * 14];
    red2[jg][k] = s;
  }
  float alpha = prelu[0];
  __syncthreads();
  if (t < 14) {
    float s = 0.f;
#pragma unroll
    for (int jg = 0; jg < 8; ++jg) s += red2[jg][t];
    Sm[t] = s;
  }
  __syncthreads();
  if (t < 64) {
    int o = t;
    float w0 = cw[o * 4 + 0], w1 = cw[o * 4 + 1];
    float w2 = cw[o * 4 + 2], w3 = cw[o * 4 + 3];
    float bo = cb_[o];
    const float cnt = (float)(NP * NS);
    float wS1 = w0 * Sm[0] + w1 * Sm[1] + w2 * Sm[2] + w3 * Sm[3];
    float q = w0 * w0 * Sm[4] + w1 * w1 * Sm[8] + w2 * w2 * Sm[11] +
              w3 * w3 * Sm[13] +
              2.f * (w0 * w1 * Sm[5] + w0 * w2 * Sm[6] + w0 * w3 * Sm[7] +
                     w1 * w2 * Sm[9] + w1 * w3 * Sm[10] + w2 * w3 * Sm[12]);
    SxA[o] = wS1 + bo * cnt;
    SxxA[o] = q + 2.f * bo * wS1 + bo * bo * cnt;
  }
  __syncthreads();
  if (t < 64) {
    int o = t, g = o >> 3;
    const float cnt = (float)(NP * NS);
    float sm = 0.f, s2 = 0.f;
#pragma unroll
    for (int k = 0; k < 8; ++k) {
      sm += SxA[g * 8 + k];
      s2 += SxxA[g * 8 + k];
    }
    float mean = sm / (cnt * 8.f);
    float e2 = s2 / (cnt * 8.f);
    float var = e2 - mean * mean;
    float inv = rsqrtf(var + 1e-5f);
    float A = gamma[o] * inv;
    Av[o] = A;
    Bv[o] = beta[o] - mean * A;
  }
  __syncthreads();
  {
    int o = t & 63;
    int pw = t >> 6;
    float w0 = cw[o * 4 + 0], w1 = cw[o * 4 + 1];
    float w2 = cw[o * 4 + 2], w3 = cw[o * 4 + 3];
    float A = Av[o], Bc = Bv[o], bb = cb_[o];
    float* vsf = (float*)vs4;
#pragma unroll
    for (int i = 0; i < 4; ++i) {
      int p = pw * 4 + i;
      float mx = -INFINITY;
#pragma unroll
      for (int s = 0; s < NS; ++s) {
        float4 f = fs4[p * 8 + s];
        float x = fmaf(w0, f.x, fmaf(w1, f.y, fmaf(w2, f.z, fmaf(w3, f.w, bb))));
        float y = fmaf(A, x, Bc);
        y = (y >= 0.f) ? y : alpha * y;
        mx = fmaxf(mx, y);
      }
      vsf[(p * 16 + ((o >> 2) ^ ((p >> 2) & 7))) * 4 + (o & 3)] = mx;
    }
  }
  __syncthreads();
  {
    int ti = t >> 3;
    int tj = t & 7;
    float acc[2][2];
#pragma unroll
    for (int oi = 0; oi < 2; ++oi)
#pragma unroll
      for (int pj = 0; pj < 2; ++pj) acc[oi][pj] = 0.f;
#pragma unroll
    for (int g = 0; g < 16; ++g) {
      float4 vv[2], ww[2];
#pragma unroll
      for (int pj = 0; pj < 2; ++pj) {
        int p = tj * 2 + pj;
        vv[pj] = vs4[p * 16 + (g ^ ((p >> 2) & 7))];
      }
#pragma unroll
      for (int oi = 0; oi < 2; ++oi) {
        int oo = ti * 2 + oi;
        ww[oi] = ow4[oo * 16 + (g ^ ((oo >> 2) & 7))];
      }
#pragma unroll
      for (int oi = 0; oi < 2; ++oi)
#pragma unroll
        for (int pj = 0; pj < 2; ++pj) {
          acc[oi][pj] = fmaf(ww[oi].x, vv[pj].x, acc[oi][pj]);
          acc[oi][pj] = fmaf(ww[oi].y, vv[pj].y, acc[oi][pj]);
          acc[oi][pj] = fmaf(ww[oi].z, vv[pj].z, acc[oi][pj]);
          acc[oi][pj] = fmaf(ww[oi].w, vv[pj].w, acc[oi][pj]);
        }
    }
#pragma unroll
    for (int oi = 0; oi < 2; ++oi) {
      int oo = ti * 2 + oi;
      float bb = ob_[oo];
      float2 r;
      r.x = acc[oi][0] + bb;
      r.y = acc[oi][1] + bb;
      *(float2*)&out[((size_t)b * CCH + oo) * NP + n0 + tj * 2] = r;
    }
  }
}

extern "C" void kernel_launch(void* const* d_in, const int* in_sizes, int n_in,
                              void* d_out, int out_size, void* d_ws, size_t ws_size,
                              hipStream_t stream) {
  const float* coords = (const float*)d_in[0];
  const float* xyz2 = (const float*)d_in[1];
  const float* fmap1 = (const float*)d_in[2];
  const float* fmap2 = (const float*)d_in[3];
  const float* conv_w = (const float*)d_in[4];
  const float* conv_b = (const float*)d_in[5];
  const float* gamma = (const float*)d_in[6];
  const float* beta = (const float*)d_in[7];
  const float* prelu = (const float*)d_in[8];
  const float* out_w = (const float*)d_in[9];
  const float* out_b = (const float*)d_in[10];
  float* out = (float*)d_out;
  float* ws = (float*)d_ws;

  const size_t BND = (size_t)B * NP * DIM;
  const size_t FEAT = (size_t)B * NP * NS * 4;
  const size_t PARTS = (size_t)B * 256 * 14;
  size_t needT = (BND + FEAT + PARTS + 512) * sizeof(float);
  int useT = (ws_size >= needT) ? 1 : 0;

  float* f2T = ws;
  float* featp = useT ? (f2T + BND) : ws;
  float* parts = featp + FEAT;

  if (useT)
    k_transpose<<<dim3(B * (NP / 32)), dim3(256), 0, stream>>>(fmap2, f2T);
  k_bqcorr<<<dim3(1024), dim3(256), 0, stream>>>(
      coords, xyz2, fmap1, fmap2, f2T, featp, parts, useT);
  kB_out<<<dim3(B * (NP / 16)), dim3(256), 0, stream>>>(
      featp, parts, conv_w, conv_b, gamma, beta, prelu, out_w, out_b, out);
}